// Round 11
// baseline (95.264 us; speedup 1.0000x reference)
//
#include <hip/hip_runtime.h>

// Problem constants (match reference)
#define NB 8
#define HH 352
#define WW 352
#define TX 32
#define TY 32
// AoS tap tile: taps look down/sideways only -> rows gy in [y0, y0+36],
// cols gx in [x0-5, x0+36].
#define TLH 37
#define TLW 42
#define LSTRIDE 43               // float4 units, odd -> (3*row + col) mod 8 covers all bank quads
// mask plane: rows gy in [y0, y0+36], cols gx in [x0-5, x0+36]
#define MH 37
#define MW 42
#define MSTRIDE 44               // mult of 4 floats for aligned b128 reads
#define TILES_X 11
#define TILES_Y 11
#define NBLK (TILES_X * TILES_Y * NB)   // 968 = 8 XCDs x 121 tiles (one image each)

// Pre-scale rgb by sqrt(ALPHA * log2(e)) so wgt = exp2(-sum(d^2))
#define RGB_SCALE 16.98644781888824f

typedef float f32x2 __attribute__((ext_vector_type(2)));

__device__ __forceinline__ float elem(float4 q, int c) {
    return c == 0 ? q.x : c == 1 ? q.y : c == 2 ? q.z : q.w;
}

// One window float4 vs a PAIR of pre-negated packed centers, with mask-weight mq.
__device__ __forceinline__ void tap_pair(const float4& w, float mq,
                                         f32x2 ncx, f32x2 ncy, f32x2 ncz, f32x2 ncw,
                                         f32x2& accP, f32x2& accQ) {
    f32x2 d0 = ncx + w.x;        // pk_add, scalar broadcast
    f32x2 d1 = ncy + w.y;
    f32x2 d2 = ncz + w.z;
    f32x2 s  = d0 * d0;
    s += d1 * d1;                // pk_fma
    s += d2 * d2;
    f32x2 ds = ncw + w.w;
    f32x2 v;
    v.x = __builtin_amdgcn_exp2f(-s.x) * fabsf(ds.x);
    v.y = __builtin_amdgcn_exp2f(-s.y) * fabsf(ds.y);
    accP += v;                   // pk_add
    f32x2 mqv; mqv.x = mq; mqv.y = mq;
    accQ += v * mqv;             // pk_fma
}

__device__ __forceinline__ void tap_scalar(const float4& w, float mq,
                                           float ncx, float ncy, float ncz, float ncw,
                                           float& aP, float& aQ) {
    float d0 = w.x + ncx, d1 = w.y + ncy, d2 = w.z + ncz;
    float s = fmaf(d0, d0, fmaf(d1, d1, d2 * d2));
    float v = __builtin_amdgcn_exp2f(-s) * fabsf(w.w + ncw);
    aP += v;
    aQ = fmaf(v, mq, aQ);
}

// LDS budget ~33 KB -> 4 blocks/CU by LDS. Launch bounds (256,2): R6 showed
// (256,4) forces a 64-VGPR cap -> scratch spills; (256,2) -> no cap pathology.
// Separate finalize kernel: R8 showed per-block cross-XCD fence costs ~14 us.
__global__ __launch_bounds__(256, 2)
void btm_loss_kernel(const float* __restrict__ pred,
                     const float* __restrict__ feat,
                     float2* __restrict__ partials) {
    __shared__ __align__(16) float4 tile[TLH * LSTRIDE];  // 25.4 KB AoS (r,g,b,sal)
    __shared__ __align__(16) float  maskp[MH * MSTRIDE];  // 6.5 KB mask plane
    __shared__ unsigned long long hbuf[41];               // horiz 5-OR of lbl bits
    __shared__ unsigned long long nhbuf[41];              // horiz 5-OR of ~lbl bits
    __shared__ unsigned long long Mbuf[37];               // final mask bits per row
    __shared__ float2 wred[4];

    // XCD-aware swizzle: 968 = 8 x 121 -> XCD k gets all 121 tiles of image k;
    // halo re-reads hit that XCD's private L2. partials indexed by ORIGINAL bid
    // -> finalize order, and output bits, unchanged. (R10: -3 us)
    const int braw = blockIdx.x;
    const int bid  = (braw & 7) * (TILES_X * TILES_Y) + (braw >> 3);  // bijective
    const int tx_blk = bid % TILES_X;
    const int ty_blk = (bid / TILES_X) % TILES_Y;
    const int n = bid / (TILES_X * TILES_Y);
    const int x0 = tx_blk * TX;
    const int y0 = ty_blk * TY;

    const size_t plane = (size_t)HH * WW;
    const float* fr = feat + ((size_t)n * 3 + 0) * plane;
    const float* fg = feat + ((size_t)n * 3 + 1) * plane;
    const float* fb = feat + ((size_t)n * 3 + 2) * plane;
    const float* ps = pred + (size_t)n * plane;

    const int t = threadIdx.x;

    // ---- bit-mask build: one sal row per wave-iteration via ballot ----
    {
        const int wv = t >> 6, ln = t & 63;
        for (int r = wv; r < 41; r += 4) {
            int gy = y0 + r - 2;
            int gx = x0 - 7 + ln;
            bool inimg = ((unsigned)gy < (unsigned)HH) &&
                         ((unsigned)gx < (unsigned)WW) && (ln < 46);
            float sv = inimg ? ps[gy * WW + gx] : 0.f;
            unsigned long long lb = __ballot(inimg && (sv > 0.5f));
            unsigned long long nb = __ballot(inimg && (sv <= 0.5f));
            unsigned long long a2 = lb | (lb >> 1); a2 |= (a2 >> 2); a2 |= (lb >> 4);
            unsigned long long b2 = nb | (nb >> 1); b2 |= (b2 >> 2); b2 |= (nb >> 4);
            if (ln == 0) { hbuf[r] = a2; nhbuf[r] = b2; }
        }
    }

    // ---- stage tap tile (incremental row/col, no per-iter division) ----
    {
        int lr = t / TLW;
        int lc = t - lr * TLW;
        for (int i = t; i < TLH * TLW; i += 256) {
            int gy = y0 + lr;
            int gx = x0 + lc - 5;
            float4 v = make_float4(0.f, 0.f, 0.f, 0.f);
            if ((unsigned)gy < (unsigned)HH && (unsigned)gx < (unsigned)WW) {
                int gi = gy * WW + gx;
                v.x = fr[gi] * RGB_SCALE;
                v.y = fg[gi] * RGB_SCALE;
                v.z = fb[gi] * RGB_SCALE;
                v.w = ps[gi];
            }
            tile[lr * LSTRIDE + lc] = v;
            lc += 256 - 6 * TLW;         // 256 = 6*42 + 4
            lr += 6;
            if (lc >= TLW) { lc -= TLW; lr += 1; }
        }
    }
    __syncthreads();

    // ---- vertical 5-OR + q-position validity -> mask bits per row ----
    if (t < 37) {
        int lo = 5 - x0; if (lo < 0) lo = 0;
        int hi = WW + 5 - x0; if (hi > 42) hi = 42;
        unsigned long long cm = ((1ull << hi) - 1) & ~((1ull << lo) - 1);
        unsigned long long D = hbuf[t], E = nhbuf[t];
        #pragma unroll
        for (int k = 1; k < 5; ++k) { D |= hbuf[t + k]; E |= nhbuf[t + k]; }
        Mbuf[t] = (y0 + t < HH) ? (D & E & cm) : 0ull;
    }
    __syncthreads();

    // ---- expand mask bits -> float plane ----
    {
        int mr = t / MW;
        int mc = t - mr * MW;
        for (int i = t; i < MH * MW; i += 256) {
            maskp[mr * MSTRIDE + mc] = (float)((Mbuf[mr] >> mc) & 1ull);
            mc += 256 - 6 * MW;
            mr += 6;
            if (mc >= MW) { mc -= MW; mr += 1; }
        }
    }
    __syncthreads();

    // ---- half-window pair taps: each thread owns 4 x-adjacent pixels ----
    const int txq = t & 7;       // 0..7
    const int ty  = t >> 3;      // 0..31
    const int px0 = txq * 4;

    const float4* trow = tile + ty * LSTRIDE + px0;
    const float*  mrow = maskp + ty * MSTRIDE + px0;

    float4 c0 = trow[5], c1 = trow[6], c2 = trow[7], c3 = trow[8];
    f32x2 n01x = {-c0.x, -c1.x}, n01y = {-c0.y, -c1.y}, n01z = {-c0.z, -c1.z}, n01w = {-c0.w, -c1.w};
    f32x2 n23x = {-c2.x, -c3.x}, n23y = {-c2.y, -c3.y}, n23z = {-c2.z, -c3.z}, n23w = {-c2.w, -c3.w};

    f32x2 aP01 = {0.f, 0.f}, aP23 = {0.f, 0.f};
    f32x2 aQ01 = {0.f, 0.f}, aQ23 = {0.f, 0.f};
    float sP0 = 0.f, sP1 = 0.f, sP2 = 0.f, sP3 = 0.f, sQ = 0.f;

    // dy = 0 row: pairs to the RIGHT only (dx 1..5). Window cols j = 6..13.
    float4 mf0[3];
    #pragma unroll
    for (int q = 0; q < 3; ++q) mf0[q] = *(const float4*)&mrow[4 + 4 * q];
    {
        float4 w0[8];
        #pragma unroll
        for (int j = 0; j < 8; ++j) w0[j] = trow[6 + j];

        tap_scalar(w0[0], elem(mf0[0], 2), n01x.x, n01y.x, n01z.x, n01w.x, sP0, sQ); // c0 dx=1
        #pragma unroll
        for (int j = 1; j <= 4; ++j)
            tap_pair(w0[j], elem(mf0[(j + 2) >> 2], (j + 2) & 3), n01x, n01y, n01z, n01w, aP01, aQ01);
        tap_scalar(w0[5], elem(mf0[1], 3), n01x.y, n01y.y, n01z.y, n01w.y, sP1, sQ); // c1 dx=5
        tap_scalar(w0[2], elem(mf0[1], 0), n23x.x, n23y.x, n23z.x, n23w.x, sP2, sQ); // c2 dx=1
        #pragma unroll
        for (int j = 3; j <= 6; ++j)
            tap_pair(w0[j], elem(mf0[(j + 2) >> 2], (j + 2) & 3), n23x, n23y, n23z, n23w, aP23, aQ23);
        tap_scalar(w0[7], elem(mf0[2], 1), n23x.y, n23y.y, n23z.y, n23w.y, sP3, sQ); // c3 dx=5
    }

    // dy = 1..5: register double-buffered pipeline over rows (fence-free).
    // wA/wB are named 14-float4 buffers rotated through the rows; next-row
    // loads are interleaved BETWEEN the current row's two tap half-sets, so
    // their ds_read latency hides under ~300 VALU cycles of tap work.
    // The #pragma unroll 1 outer loop (loop-carried wA/wB deps) stops the
    // compiler from hoisting all rows' loads (R4: full hoist -> spill).
    // NO sched_barrier (R2: fences -> fixed regions -> spill).
    {
        float4 wA[14], wB[14], mfc[4];

        #define LOADW(dst, row) do {                                         \
            const float4* _rp = trow + (row) * LSTRIDE;                      \
            _Pragma("unroll")                                                \
            for (int j = 0; j < 14; ++j) dst[j] = _rp[j];                    \
        } while (0)
        #define LOADM(row) do {                                              \
            const float* _mp = mrow + (row) * MSTRIDE;                       \
            _Pragma("unroll")                                                \
            for (int q = 0; q < 4; ++q) mfc[q] = *(const float4*)&_mp[4 * q];\
        } while (0)
        #define COMP_C01(w) do {                                             \
            tap_scalar(w[0], elem(mfc[0], 0), n01x.x, n01y.x, n01z.x, n01w.x, sP0, sQ); \
            _Pragma("unroll")                                                \
            for (int j = 1; j <= 10; ++j)                                    \
                tap_pair(w[j], elem(mfc[j >> 2], j & 3), n01x, n01y, n01z, n01w, aP01, aQ01); \
            tap_scalar(w[11], elem(mfc[2], 3), n01x.y, n01y.y, n01z.y, n01w.y, sP1, sQ); \
        } while (0)
        #define COMP_C23(w) do {                                             \
            tap_scalar(w[2], elem(mfc[0], 2), n23x.x, n23y.x, n23z.x, n23w.x, sP2, sQ); \
            _Pragma("unroll")                                                \
            for (int j = 3; j <= 12; ++j)                                    \
                tap_pair(w[j], elem(mfc[j >> 2], j & 3), n23x, n23y, n23z, n23w, aP23, aQ23); \
            tap_scalar(w[13], elem(mfc[3], 1), n23x.y, n23y.y, n23z.y, n23w.y, sP3, sQ); \
        } while (0)

        LOADW(wA, 1);
        #pragma unroll 1
        for (int k = 0; k < 2; ++k) {
            const int r = 2 * k + 1;       // rows r, r+1 computed; r+1, r+2 loaded
            LOADM(r);
            COMP_C01(wA);
            LOADW(wB, r + 1);              // issue next row under c23 compute
            COMP_C23(wA);
            LOADM(r + 1);
            COMP_C01(wB);
            LOADW(wA, r + 2);              // k=0 -> row 3, k=1 -> row 5
            COMP_C23(wB);
        }
        LOADM(5);                          // epilogue: row 5 in wA
        COMP_C01(wA);
        COMP_C23(wA);

        #undef LOADW
        #undef LOADM
        #undef COMP_C01
        #undef COMP_C23
    }

    // ---- combine: num = sum_i m_i*(A_H(i) + pad_i) + sum(v*m_q) ----
    float m0 = mf0[0].y, m1 = mf0[0].z, m2 = mf0[0].w, m3 = mf0[1].x;
    float e0 = aP01.x + sP0, e1 = aP01.y + sP1;
    float e2 = aP23.x + sP2, e3 = aP23.y + sP3;

    // Upper/left pad taps (closed form): all pads identical for a pixel.
    const bool padblk = (ty_blk == 0) || (tx_blk == 0) || (tx_blk == TILES_X - 1);
    if (padblk) {
        const int gy = y0 + ty;
        const int nneg = (5 - gy) > 0 ? (5 - gy) : 0;
        #pragma unroll
        for (int i = 0; i < 4; ++i) {
            const int gx = x0 + px0 + i;
            const int cl = (5 - gx) > 0 ? (5 - gx) : 0;
            const int cr = (gx - 346) > 0 ? (gx - 346) : 0;
            const int np = nneg * 11 + (5 - nneg) * (cl + cr) + cl;
            if (np > 0) {
                float4 ci = (i == 0) ? c0 : (i == 1) ? c1 : (i == 2) ? c2 : c3;
                float s2 = fmaf(ci.x, ci.x, fmaf(ci.y, ci.y, ci.z * ci.z));
                float vp = __builtin_amdgcn_exp2f(-s2) * ci.w * (float)np;
                if (i == 0) e0 += vp; else if (i == 1) e1 += vp;
                else if (i == 2) e2 += vp; else e3 += vp;
            }
        }
    }

    float num = fmaf(m0, e0, fmaf(m1, e1, fmaf(m2, e2, m3 * e3)))
              + ((aQ01.x + aQ01.y) + (aQ23.x + aQ23.y)) + sQ;
    float den = (m0 + m1) + (m2 + m3);

    // ---- wave reduce -> block reduce -> deterministic partial store ----
    #pragma unroll
    for (int off = 32; off > 0; off >>= 1) {
        num += __shfl_down(num, off, 64);
        den += __shfl_down(den, off, 64);
    }
    const int wid  = t >> 6;
    const int lane = t & 63;
    if (lane == 0) wred[wid] = make_float2(num, den);
    __syncthreads();
    if (t == 0) {
        float2 a = wred[0];
        #pragma unroll
        for (int w2 = 1; w2 < 4; ++w2) { a.x += wred[w2].x; a.y += wred[w2].y; }
        partials[bid] = a;   // ORIGINAL bid -> finalize order bit-identical
    }
}

__global__ __launch_bounds__(256)
void btm_finalize_kernel(const float2* __restrict__ partials,
                         float* __restrict__ out) {
    __shared__ float2 wred[4];
    float num = 0.f, den = 0.f;
    for (int i = threadIdx.x; i < NBLK; i += 256) {
        float2 p = partials[i];
        num += p.x;
        den += p.y;
    }
    #pragma unroll
    for (int off = 32; off > 0; off >>= 1) {
        num += __shfl_down(num, off, 64);
        den += __shfl_down(den, off, 64);
    }
    int wid  = threadIdx.x >> 6;
    int lane = threadIdx.x & 63;
    if (lane == 0) wred[wid] = make_float2(num, den);
    __syncthreads();
    if (threadIdx.x == 0) {
        float2 a = wred[0];
        #pragma unroll
        for (int w = 1; w < 4; ++w) { a.x += wred[w].x; a.y += wred[w].y; }
        out[0] = a.x / (a.y + 1e-6f);
    }
}

extern "C" void kernel_launch(void* const* d_in, const int* in_sizes, int n_in,
                              void* d_out, int out_size, void* d_ws, size_t ws_size,
                              hipStream_t stream) {
    const float* pred = (const float*)d_in[0];  // (8,1,352,352) fp32
    const float* feat = (const float*)d_in[1];  // (8,3,352,352) fp32
    float* out = (float*)d_out;                 // scalar fp32
    float2* partials = (float2*)d_ws;           // NBLK float2 = 7.7 KB

    btm_loss_kernel<<<dim3(NBLK), dim3(256), 0, stream>>>(pred, feat, partials);
    btm_finalize_kernel<<<dim3(1), dim3(256), 0, stream>>>(partials, out);
}

// Round 12
// 90.039 us; speedup vs baseline: 1.0580x; 1.0580x over previous
//
#include <hip/hip_runtime.h>

// Problem constants (match reference)
#define NB 8
#define HH 352
#define WW 352
#define TX 32
#define TY 32
// AoS tap tile: taps look down/sideways only -> rows gy in [y0, y0+36],
// cols gx in [x0-5, x0+36].
#define TLH 37
#define TLW 42
#define LSTRIDE 43               // float4 units, odd -> banks spread
// mask plane: rows gy in [y0, y0+36], cols gx in [x0-5, x0+36]
#define MH 37
#define MW 42
#define MSTRIDE 44               // mult of 4 floats
#define TILES_X 11
#define TILES_Y 11
#define NBLK (TILES_X * TILES_Y * NB)   // 968 = 8 XCDs x 121 tiles (one image each)

// Pre-scale rgb by sqrt(ALPHA * log2(e)) so wgt = exp2(-sum(d^2))
#define RGB_SCALE 16.98644781888824f

typedef float f32x2 __attribute__((ext_vector_type(2)));

// One window float4 vs the thread's pre-negated packed center pair (c0,c1),
// with mask-weight mq of the shared window pixel q.
__device__ __forceinline__ void tap_pair(const float4& w, float mq,
                                         f32x2 ncx, f32x2 ncy, f32x2 ncz, f32x2 ncw,
                                         f32x2& accP, f32x2& accQ) {
    f32x2 d0 = ncx + w.x;        // pk_add, scalar broadcast
    f32x2 d1 = ncy + w.y;
    f32x2 d2 = ncz + w.z;
    f32x2 s  = d0 * d0;
    s += d1 * d1;                // pk_fma
    s += d2 * d2;
    f32x2 ds = ncw + w.w;
    f32x2 v;
    v.x = __builtin_amdgcn_exp2f(-s.x) * fabsf(ds.x);
    v.y = __builtin_amdgcn_exp2f(-s.y) * fabsf(ds.y);
    accP += v;                   // pk_add
    f32x2 mqv; mqv.x = mq; mqv.y = mq;
    accQ += v * mqv;             // pk_fma
}

__device__ __forceinline__ void tap_scalar(const float4& w, float mq,
                                           float ncx, float ncy, float ncz, float ncw,
                                           float& aP, float& aQ) {
    float d0 = w.x + ncx, d1 = w.y + ncy, d2 = w.z + ncz;
    float s = fmaf(d0, d0, fmaf(d1, d1, d2 * d2));
    float v = __builtin_amdgcn_exp2f(-s) * fabsf(w.w + ncw);
    aP += v;
    aQ = fmaf(v, mq, aQ);
}

// 512 threads x 2 px: per-wave program halves vs R10 (4 px/thread), waves/block
// 4 -> 8. LDS ~33 KB -> up to 4 blocks x 512 thr = 2048/CU (HW max). Rationale:
// OccupancyPercent pinned ~21% all session; ILP pipelining falsified (R2/R11);
// TLP via blocks/CU falsified (R5->R7); waves-per-work untested until now.
// No launch_bounds cap (R6: forced 64-VGPR cap -> spills).
__global__ __launch_bounds__(512)
void btm_loss_kernel(const float* __restrict__ pred,
                     const float* __restrict__ feat,
                     float2* __restrict__ partials) {
    __shared__ __align__(16) float4 tile[TLH * LSTRIDE];  // 25.4 KB AoS (r,g,b,sal)
    __shared__ __align__(16) float  maskp[MH * MSTRIDE];  // 6.5 KB mask plane
    __shared__ unsigned long long hbuf[41];               // horiz 5-OR of lbl bits
    __shared__ unsigned long long nhbuf[41];              // horiz 5-OR of ~lbl bits
    __shared__ unsigned long long Mbuf[37];               // final mask bits per row
    __shared__ float2 wred[8];

    // XCD-aware swizzle (R10: -3 us): 968 = 8 x 121 -> XCD k gets image k.
    // partials indexed by ORIGINAL bid -> finalize order unchanged.
    const int braw = blockIdx.x;
    const int bid  = (braw & 7) * (TILES_X * TILES_Y) + (braw >> 3);  // bijective
    const int tx_blk = bid % TILES_X;
    const int ty_blk = (bid / TILES_X) % TILES_Y;
    const int n = bid / (TILES_X * TILES_Y);
    const int x0 = tx_blk * TX;
    const int y0 = ty_blk * TY;

    const size_t plane = (size_t)HH * WW;
    const float* fr = feat + ((size_t)n * 3 + 0) * plane;
    const float* fg = feat + ((size_t)n * 3 + 1) * plane;
    const float* fb = feat + ((size_t)n * 3 + 2) * plane;
    const float* ps = pred + (size_t)n * plane;

    const int t = threadIdx.x;

    // ---- bit-mask build: one sal row per wave via ballot (8 waves) ----
    {
        const int wv = t >> 6, ln = t & 63;
        for (int r = wv; r < 41; r += 8) {
            int gy = y0 + r - 2;
            int gx = x0 - 7 + ln;
            bool inimg = ((unsigned)gy < (unsigned)HH) &&
                         ((unsigned)gx < (unsigned)WW) && (ln < 46);
            float sv = inimg ? ps[gy * WW + gx] : 0.f;
            unsigned long long lb = __ballot(inimg && (sv > 0.5f));
            unsigned long long nb = __ballot(inimg && (sv <= 0.5f));
            unsigned long long a2 = lb | (lb >> 1); a2 |= (a2 >> 2); a2 |= (lb >> 4);
            unsigned long long b2 = nb | (nb >> 1); b2 |= (b2 >> 2); b2 |= (nb >> 4);
            if (ln == 0) { hbuf[r] = a2; nhbuf[r] = b2; }
        }
    }

    // ---- stage tap tile ----
    for (int i = t; i < TLH * TLW; i += 512) {
        int lr = i / TLW;
        int lc = i - lr * TLW;
        int gy = y0 + lr;
        int gx = x0 + lc - 5;
        float4 v = make_float4(0.f, 0.f, 0.f, 0.f);
        if ((unsigned)gy < (unsigned)HH && (unsigned)gx < (unsigned)WW) {
            int gi = gy * WW + gx;
            v.x = fr[gi] * RGB_SCALE;
            v.y = fg[gi] * RGB_SCALE;
            v.z = fb[gi] * RGB_SCALE;
            v.w = ps[gi];
        }
        tile[lr * LSTRIDE + lc] = v;
    }
    __syncthreads();

    // ---- vertical 5-OR + q-position validity -> mask bits per row ----
    if (t < 37) {
        int lo = 5 - x0; if (lo < 0) lo = 0;
        int hi = WW + 5 - x0; if (hi > 42) hi = 42;
        unsigned long long cm = ((1ull << hi) - 1) & ~((1ull << lo) - 1);
        unsigned long long D = hbuf[t], E = nhbuf[t];
        #pragma unroll
        for (int k = 1; k < 5; ++k) { D |= hbuf[t + k]; E |= nhbuf[t + k]; }
        Mbuf[t] = (y0 + t < HH) ? (D & E & cm) : 0ull;
    }
    __syncthreads();

    // ---- expand mask bits -> float plane ----
    for (int i = t; i < MH * MW; i += 512) {
        int mr = i / MW, mc = i - mr * MW;
        maskp[mr * MSTRIDE + mc] = (float)((Mbuf[mr] >> mc) & 1ull);
    }
    __syncthreads();

    // ---- half-window pair taps: each thread owns 2 x-adjacent pixels ----
    const int txq = t & 15;      // 0..15
    const int ty  = t >> 4;      // 0..31
    const int px0 = txq * 2;

    // trow[dy*LSTRIDE + j] = window col j (gx = x0+px0-5+j). Centers at j=5,6.
    const float4* trow = tile + ty * LSTRIDE + px0;
    const float*  mrow = maskp + ty * MSTRIDE + px0;   // mrow[k] = mask col px0+k

    float4 c0 = trow[5], c1 = trow[6];
    f32x2 ncx = {-c0.x, -c1.x}, ncy = {-c0.y, -c1.y},
          ncz = {-c0.z, -c1.z}, ncw = {-c0.w, -c1.w};

    f32x2 aP = {0.f, 0.f}, aQ = {0.f, 0.f};
    float sP0 = 0.f, sP1 = 0.f, sQ = 0.f;
    float m0, m1;

    // dy = 0 row: unordered pairs to the RIGHT only.
    //   scalar c0 @ j=6 (dx=1); pairs j=7..10 (c0 dx 2..5 / c1 dx 1..4);
    //   scalar c1 @ j=11 (dx=5).
    // Mask float2 reads at even offsets (8B-aligned): cols {4,5},{6,7},{8,9},{10,11}.
    {
        float2 ma = *(const float2*)&mrow[4];    // cols px0+4, px0+5
        float2 mb = *(const float2*)&mrow[6];    // cols px0+6, px0+7
        float2 mc2 = *(const float2*)&mrow[8];   // cols px0+8, px0+9
        float2 md = *(const float2*)&mrow[10];   // cols px0+10, px0+11
        m0 = ma.y;                               // mask of pixel px0   (col px0+5)
        m1 = mb.x;                               // mask of pixel px0+1 (col px0+6)

        float4 w6 = trow[6], w7 = trow[7], w8 = trow[8], w9 = trow[9],
               w10 = trow[10], w11 = trow[11];
        tap_scalar(w6,  mb.x, ncx.x, ncy.x, ncz.x, ncw.x, sP0, sQ);  // c0 dx=1
        tap_pair(w7,  mb.y,  ncx, ncy, ncz, ncw, aP, aQ);
        tap_pair(w8,  mc2.x, ncx, ncy, ncz, ncw, aP, aQ);
        tap_pair(w9,  mc2.y, ncx, ncy, ncz, ncw, aP, aQ);
        tap_pair(w10, md.x,  ncx, ncy, ncz, ncw, aP, aQ);
        tap_scalar(w11, md.y, ncx.y, ncy.y, ncz.y, ncw.y, sP1, sQ);  // c1 dx=5
    }

    // dy = 1..5 rows: full dx range. Window cols j = 0..11 (12 b128).
    //   scalar c0 @ j=0 (dx=-5); pairs j=1..10; scalar c1 @ j=11 (dx=+5).
    // KEEP ROLLED (unroll 1): full unroll hoists all rows' LDS loads -> spill
    // (R4). Rolled, the compiler JIT-sinks ds_reads with small liveness.
    #pragma unroll 1
    for (int dy = 1; dy <= 5; ++dy) {
        const float4* wr = trow + dy * LSTRIDE;
        const float*  mr = mrow + dy * MSTRIDE;
        float4 w[12];
        #pragma unroll
        for (int j = 0; j < 12; ++j) w[j] = wr[j];
        float2 mp[6];
        #pragma unroll
        for (int q = 0; q < 6; ++q) mp[q] = *(const float2*)&mr[2 * q];

        tap_scalar(w[0], mp[0].x, ncx.x, ncy.x, ncz.x, ncw.x, sP0, sQ);  // c0 dx=-5
        #pragma unroll
        for (int j = 1; j <= 10; ++j) {
            float mq = (j & 1) ? mp[j >> 1].y : mp[j >> 1].x;
            tap_pair(w[j], mq, ncx, ncy, ncz, ncw, aP, aQ);
        }
        tap_scalar(w[11], mp[5].y, ncx.y, ncy.y, ncz.y, ncw.y, sP1, sQ); // c1 dx=+5
    }

    // ---- combine: num = sum_i m_i*(A_H(i) + pad_i) + sum(v*m_q) ----
    float e0 = aP.x + sP0, e1 = aP.y + sP1;

    // Upper/left pad taps (closed form): all pads identical for a pixel.
    const bool padblk = (ty_blk == 0) || (tx_blk == 0) || (tx_blk == TILES_X - 1);
    if (padblk) {
        const int gy = y0 + ty;
        const int nneg = (5 - gy) > 0 ? (5 - gy) : 0;   // # fully-pad rows above
        #pragma unroll
        for (int i = 0; i < 2; ++i) {
            const int gx = x0 + px0 + i;
            const int cl = (5 - gx) > 0 ? (5 - gx) : 0;
            const int cr = (gx - 346) > 0 ? (gx - 346) : 0;
            const int np = nneg * 11 + (5 - nneg) * (cl + cr) + cl;
            if (np > 0) {
                float4 ci = (i == 0) ? c0 : c1;
                float s2 = fmaf(ci.x, ci.x, fmaf(ci.y, ci.y, ci.z * ci.z));
                float vp = __builtin_amdgcn_exp2f(-s2) * ci.w * (float)np;
                if (i == 0) e0 += vp; else e1 += vp;
            }
        }
    }

    float num = fmaf(m0, e0, m1 * e1) + (aQ.x + aQ.y) + sQ;
    float den = m0 + m1;

    // ---- wave reduce -> block reduce -> deterministic partial store ----
    #pragma unroll
    for (int off = 32; off > 0; off >>= 1) {
        num += __shfl_down(num, off, 64);
        den += __shfl_down(den, off, 64);
    }
    const int wid  = t >> 6;
    const int lane = t & 63;
    if (lane == 0) wred[wid] = make_float2(num, den);
    __syncthreads();
    if (t == 0) {
        float2 a = wred[0];
        #pragma unroll
        for (int w2 = 1; w2 < 8; ++w2) { a.x += wred[w2].x; a.y += wred[w2].y; }
        partials[bid] = a;   // ORIGINAL bid -> finalize order unchanged
    }
}

__global__ __launch_bounds__(256)
void btm_finalize_kernel(const float2* __restrict__ partials,
                         float* __restrict__ out) {
    __shared__ float2 wred[4];
    float num = 0.f, den = 0.f;
    for (int i = threadIdx.x; i < NBLK; i += 256) {
        float2 p = partials[i];
        num += p.x;
        den += p.y;
    }
    #pragma unroll
    for (int off = 32; off > 0; off >>= 1) {
        num += __shfl_down(num, off, 64);
        den += __shfl_down(den, off, 64);
    }
    int wid  = threadIdx.x >> 6;
    int lane = threadIdx.x & 63;
    if (lane == 0) wred[wid] = make_float2(num, den);
    __syncthreads();
    if (threadIdx.x == 0) {
        float2 a = wred[0];
        #pragma unroll
        for (int w = 1; w < 4; ++w) { a.x += wred[w].x; a.y += wred[w].y; }
        out[0] = a.x / (a.y + 1e-6f);
    }
}

extern "C" void kernel_launch(void* const* d_in, const int* in_sizes, int n_in,
                              void* d_out, int out_size, void* d_ws, size_t ws_size,
                              hipStream_t stream) {
    const float* pred = (const float*)d_in[0];  // (8,1,352,352) fp32
    const float* feat = (const float*)d_in[1];  // (8,3,352,352) fp32
    float* out = (float*)d_out;                 // scalar fp32
    float2* partials = (float2*)d_ws;           // NBLK float2 = 7.7 KB

    btm_loss_kernel<<<dim3(NBLK), dim3(512), 0, stream>>>(pred, feat, partials);
    btm_finalize_kernel<<<dim3(1), dim3(256), 0, stream>>>(partials, out);
}

// Round 13
// 89.345 us; speedup vs baseline: 1.0662x; 1.0078x over previous
//
#include <hip/hip_runtime.h>

// Problem constants (match reference)
#define NB 8
#define HH 352
#define WW 352
#define TX 32
#define TY 16
// AoS tap tile: taps look down/sideways only -> rows gy in [y0, y0+TY+4],
// cols gx in [x0-5, x0+36].
#define TLH 21                   // TY + 5
#define TLW 42
#define LSTRIDE 43               // float4 units, odd -> banks spread
// mask plane: rows gy in [y0, y0+TY+4], cols gx in [x0-5, x0+36]
#define MH 21
#define MW 42
#define MSTRIDE 44               // mult of 4 floats
// ballot rows: gy in [y0-2, y0+TY+6]
#define BH 25                    // TY + 9
#define TILES_X 11
#define TILES_Y 22
#define NBLK (TILES_X * TILES_Y * NB)   // 1936 = 8 XCDs x 242 tiles (one image each)

// Pre-scale rgb by sqrt(ALPHA * log2(e)) so wgt = exp2(-sum(d^2))
#define RGB_SCALE 16.98644781888824f

typedef float f32x2 __attribute__((ext_vector_type(2)));

// One window float4 vs the thread's pre-negated packed center pair (c0,c1),
// with mask-weight mq of the shared window pixel q.
__device__ __forceinline__ void tap_pair(const float4& w, float mq,
                                         f32x2 ncx, f32x2 ncy, f32x2 ncz, f32x2 ncw,
                                         f32x2& accP, f32x2& accQ) {
    f32x2 d0 = ncx + w.x;        // pk_add, scalar broadcast
    f32x2 d1 = ncy + w.y;
    f32x2 d2 = ncz + w.z;
    f32x2 s  = d0 * d0;
    s += d1 * d1;                // pk_fma
    s += d2 * d2;
    f32x2 ds = ncw + w.w;
    f32x2 v;
    v.x = __builtin_amdgcn_exp2f(-s.x) * fabsf(ds.x);
    v.y = __builtin_amdgcn_exp2f(-s.y) * fabsf(ds.y);
    accP += v;                   // pk_add
    f32x2 mqv; mqv.x = mq; mqv.y = mq;
    accQ += v * mqv;             // pk_fma
}

__device__ __forceinline__ void tap_scalar(const float4& w, float mq,
                                           float ncx, float ncy, float ncz, float ncw,
                                           float& aP, float& aQ) {
    float d0 = w.x + ncx, d1 = w.y + ncy, d2 = w.z + ncz;
    float s = fmaf(d0, d0, fmaf(d1, d1, d2 * d2));
    float v = __builtin_amdgcn_exp2f(-s) * fabsf(w.w + ncw);
    aP += v;
    aQ = fmaf(v, mq, aQ);
}

// TY=16 / 1936 blocks: R12 showed waves-per-work is the live lever, but its
// 968-block grid gave only 3.78 blocks/CU vs the 4 needed for full residency.
// Here LDS ~18.5 KB -> 8 blocks/CU capacity, grid 7.56 blocks/CU -> near-max
// 32 waves/CU for most of the run, finer drain tail. Tap code identical to R12.
// No launch_bounds min-waves cap (R6: forced 64-VGPR cap -> spills).
__global__ __launch_bounds__(256)
void btm_loss_kernel(const float* __restrict__ pred,
                     const float* __restrict__ feat,
                     float2* __restrict__ partials) {
    __shared__ __align__(16) float4 tile[TLH * LSTRIDE];  // 14.4 KB AoS (r,g,b,sal)
    __shared__ __align__(16) float  maskp[MH * MSTRIDE];  // 3.7 KB mask plane
    __shared__ unsigned long long hbuf[BH];               // horiz 5-OR of lbl bits
    __shared__ unsigned long long nhbuf[BH];              // horiz 5-OR of ~lbl bits
    __shared__ unsigned long long Mbuf[MH];               // final mask bits per row
    __shared__ float2 wred[4];

    // XCD-aware swizzle (R10: -3 us): 1936 = 8 x 242 -> XCD k gets image k.
    // partials indexed by ORIGINAL bid -> finalize order unchanged.
    const int braw = blockIdx.x;
    const int bid  = (braw & 7) * (TILES_X * TILES_Y) + (braw >> 3);  // bijective
    const int tx_blk = bid % TILES_X;
    const int ty_blk = (bid / TILES_X) % TILES_Y;
    const int n = bid / (TILES_X * TILES_Y);
    const int x0 = tx_blk * TX;
    const int y0 = ty_blk * TY;

    const size_t plane = (size_t)HH * WW;
    const float* fr = feat + ((size_t)n * 3 + 0) * plane;
    const float* fg = feat + ((size_t)n * 3 + 1) * plane;
    const float* fb = feat + ((size_t)n * 3 + 2) * plane;
    const float* ps = pred + (size_t)n * plane;

    const int t = threadIdx.x;

    // ---- bit-mask build: one sal row per wave via ballot (4 waves) ----
    {
        const int wv = t >> 6, ln = t & 63;
        for (int r = wv; r < BH; r += 4) {
            int gy = y0 + r - 2;
            int gx = x0 - 7 + ln;
            bool inimg = ((unsigned)gy < (unsigned)HH) &&
                         ((unsigned)gx < (unsigned)WW) && (ln < 46);
            float sv = inimg ? ps[gy * WW + gx] : 0.f;
            unsigned long long lb = __ballot(inimg && (sv > 0.5f));
            unsigned long long nb = __ballot(inimg && (sv <= 0.5f));
            unsigned long long a2 = lb | (lb >> 1); a2 |= (a2 >> 2); a2 |= (lb >> 4);
            unsigned long long b2 = nb | (nb >> 1); b2 |= (b2 >> 2); b2 |= (nb >> 4);
            if (ln == 0) { hbuf[r] = a2; nhbuf[r] = b2; }
        }
    }

    // ---- stage tap tile ----
    for (int i = t; i < TLH * TLW; i += 256) {
        int lr = i / TLW;
        int lc = i - lr * TLW;
        int gy = y0 + lr;
        int gx = x0 + lc - 5;
        float4 v = make_float4(0.f, 0.f, 0.f, 0.f);
        if ((unsigned)gy < (unsigned)HH && (unsigned)gx < (unsigned)WW) {
            int gi = gy * WW + gx;
            v.x = fr[gi] * RGB_SCALE;
            v.y = fg[gi] * RGB_SCALE;
            v.z = fb[gi] * RGB_SCALE;
            v.w = ps[gi];
        }
        tile[lr * LSTRIDE + lc] = v;
    }
    __syncthreads();

    // ---- vertical 5-OR + q-position validity -> mask bits per row ----
    if (t < MH) {
        int lo = 5 - x0; if (lo < 0) lo = 0;
        int hi = WW + 5 - x0; if (hi > 42) hi = 42;
        unsigned long long cm = ((1ull << hi) - 1) & ~((1ull << lo) - 1);
        unsigned long long D = hbuf[t], E = nhbuf[t];
        #pragma unroll
        for (int k = 1; k < 5; ++k) { D |= hbuf[t + k]; E |= nhbuf[t + k]; }
        Mbuf[t] = (y0 + t < HH) ? (D & E & cm) : 0ull;
    }
    __syncthreads();

    // ---- expand mask bits -> float plane ----
    for (int i = t; i < MH * MW; i += 256) {
        int mr = i / MW, mc = i - mr * MW;
        maskp[mr * MSTRIDE + mc] = (float)((Mbuf[mr] >> mc) & 1ull);
    }
    __syncthreads();

    // ---- half-window pair taps: each thread owns 2 x-adjacent pixels ----
    const int txq = t & 15;      // 0..15
    const int ty  = t >> 4;      // 0..15
    const int px0 = txq * 2;

    // trow[dy*LSTRIDE + j] = window col j (gx = x0+px0-5+j). Centers at j=5,6.
    const float4* trow = tile + ty * LSTRIDE + px0;
    const float*  mrow = maskp + ty * MSTRIDE + px0;   // mrow[k] = mask col px0+k

    float4 c0 = trow[5], c1 = trow[6];
    f32x2 ncx = {-c0.x, -c1.x}, ncy = {-c0.y, -c1.y},
          ncz = {-c0.z, -c1.z}, ncw = {-c0.w, -c1.w};

    f32x2 aP = {0.f, 0.f}, aQ = {0.f, 0.f};
    float sP0 = 0.f, sP1 = 0.f, sQ = 0.f;
    float m0, m1;

    // dy = 0 row: unordered pairs to the RIGHT only.
    //   scalar c0 @ j=6 (dx=1); pairs j=7..10 (c0 dx 2..5 / c1 dx 1..4);
    //   scalar c1 @ j=11 (dx=5).
    // Mask float2 reads at even offsets (8B-aligned).
    {
        float2 ma = *(const float2*)&mrow[4];    // cols px0+4, px0+5
        float2 mb = *(const float2*)&mrow[6];    // cols px0+6, px0+7
        float2 mc2 = *(const float2*)&mrow[8];   // cols px0+8, px0+9
        float2 md = *(const float2*)&mrow[10];   // cols px0+10, px0+11
        m0 = ma.y;                               // mask of pixel px0   (col px0+5)
        m1 = mb.x;                               // mask of pixel px0+1 (col px0+6)

        float4 w6 = trow[6], w7 = trow[7], w8 = trow[8], w9 = trow[9],
               w10 = trow[10], w11 = trow[11];
        tap_scalar(w6,  mb.x, ncx.x, ncy.x, ncz.x, ncw.x, sP0, sQ);  // c0 dx=1
        tap_pair(w7,  mb.y,  ncx, ncy, ncz, ncw, aP, aQ);
        tap_pair(w8,  mc2.x, ncx, ncy, ncz, ncw, aP, aQ);
        tap_pair(w9,  mc2.y, ncx, ncy, ncz, ncw, aP, aQ);
        tap_pair(w10, md.x,  ncx, ncy, ncz, ncw, aP, aQ);
        tap_scalar(w11, md.y, ncx.y, ncy.y, ncz.y, ncw.y, sP1, sQ);  // c1 dx=5
    }

    // dy = 1..5 rows: full dx range. Window cols j = 0..11 (12 b128).
    // KEEP ROLLED (unroll 1): full unroll hoists all rows' LDS loads -> spill
    // (R4). Rolled, the compiler JIT-sinks ds_reads with small liveness.
    #pragma unroll 1
    for (int dy = 1; dy <= 5; ++dy) {
        const float4* wr = trow + dy * LSTRIDE;
        const float*  mr = mrow + dy * MSTRIDE;
        float4 w[12];
        #pragma unroll
        for (int j = 0; j < 12; ++j) w[j] = wr[j];
        float2 mp[6];
        #pragma unroll
        for (int q = 0; q < 6; ++q) mp[q] = *(const float2*)&mr[2 * q];

        tap_scalar(w[0], mp[0].x, ncx.x, ncy.x, ncz.x, ncw.x, sP0, sQ);  // c0 dx=-5
        #pragma unroll
        for (int j = 1; j <= 10; ++j) {
            float mq = (j & 1) ? mp[j >> 1].y : mp[j >> 1].x;
            tap_pair(w[j], mq, ncx, ncy, ncz, ncw, aP, aQ);
        }
        tap_scalar(w[11], mp[5].y, ncx.y, ncy.y, ncz.y, ncw.y, sP1, sQ); // c1 dx=+5
    }

    // ---- combine: num = sum_i m_i*(A_H(i) + pad_i) + sum(v*m_q) ----
    float e0 = aP.x + sP0, e1 = aP.y + sP1;

    // Upper/left pad taps (closed form): all pads identical for a pixel.
    const bool padblk = (ty_blk == 0) || (tx_blk == 0) || (tx_blk == TILES_X - 1);
    if (padblk) {
        const int gy = y0 + ty;
        const int nneg = (5 - gy) > 0 ? (5 - gy) : 0;   // # fully-pad rows above
        #pragma unroll
        for (int i = 0; i < 2; ++i) {
            const int gx = x0 + px0 + i;
            const int cl = (5 - gx) > 0 ? (5 - gx) : 0;
            const int cr = (gx - 346) > 0 ? (gx - 346) : 0;
            const int np = nneg * 11 + (5 - nneg) * (cl + cr) + cl;
            if (np > 0) {
                float4 ci = (i == 0) ? c0 : c1;
                float s2 = fmaf(ci.x, ci.x, fmaf(ci.y, ci.y, ci.z * ci.z));
                float vp = __builtin_amdgcn_exp2f(-s2) * ci.w * (float)np;
                if (i == 0) e0 += vp; else e1 += vp;
            }
        }
    }

    float num = fmaf(m0, e0, m1 * e1) + (aQ.x + aQ.y) + sQ;
    float den = m0 + m1;

    // ---- wave reduce -> block reduce -> deterministic partial store ----
    #pragma unroll
    for (int off = 32; off > 0; off >>= 1) {
        num += __shfl_down(num, off, 64);
        den += __shfl_down(den, off, 64);
    }
    const int wid  = t >> 6;
    const int lane = t & 63;
    if (lane == 0) wred[wid] = make_float2(num, den);
    __syncthreads();
    if (t == 0) {
        float2 a = wred[0];
        #pragma unroll
        for (int w2 = 1; w2 < 4; ++w2) { a.x += wred[w2].x; a.y += wred[w2].y; }
        partials[bid] = a;   // ORIGINAL bid -> finalize order unchanged
    }
}

__global__ __launch_bounds__(256)
void btm_finalize_kernel(const float2* __restrict__ partials,
                         float* __restrict__ out) {
    __shared__ float2 wred[4];
    float num = 0.f, den = 0.f;
    for (int i = threadIdx.x; i < NBLK; i += 256) {
        float2 p = partials[i];
        num += p.x;
        den += p.y;
    }
    #pragma unroll
    for (int off = 32; off > 0; off >>= 1) {
        num += __shfl_down(num, off, 64);
        den += __shfl_down(den, off, 64);
    }
    int wid  = threadIdx.x >> 6;
    int lane = threadIdx.x & 63;
    if (lane == 0) wred[wid] = make_float2(num, den);
    __syncthreads();
    if (threadIdx.x == 0) {
        float2 a = wred[0];
        #pragma unroll
        for (int w = 1; w < 4; ++w) { a.x += wred[w].x; a.y += wred[w].y; }
        out[0] = a.x / (a.y + 1e-6f);
    }
}

extern "C" void kernel_launch(void* const* d_in, const int* in_sizes, int n_in,
                              void* d_out, int out_size, void* d_ws, size_t ws_size,
                              hipStream_t stream) {
    const float* pred = (const float*)d_in[0];  // (8,1,352,352) fp32
    const float* feat = (const float*)d_in[1];  // (8,3,352,352) fp32
    float* out = (float*)d_out;                 // scalar fp32
    float2* partials = (float2*)d_ws;           // NBLK float2 = 15.5 KB

    btm_loss_kernel<<<dim3(NBLK), dim3(256), 0, stream>>>(pred, feat, partials);
    btm_finalize_kernel<<<dim3(1), dim3(256), 0, stream>>>(partials, out);
}